// Round 2
// baseline (719.903 us; speedup 1.0000x reference)
//
#include <hip/hip_runtime.h>
#include <hip/hip_bf16.h>

#define LSPANS 4096
#define BB 32
#define HH 1024
#define DD 1024
#define VV 32000
#define K1 2048   // 2H
#define NT2 125   // V / 256

typedef unsigned short u16;
typedef __attribute__((ext_vector_type(8))) short bf16x8v;
typedef __attribute__((ext_vector_type(4))) float f32x4v;

__device__ __forceinline__ u16 f2bf(float x) {
  union { float f; unsigned u; } v; v.f = x;
  unsigned r = (v.u >> 16) & 1u;
  return (u16)((v.u + 0x7fffu + r) >> 16);
}

// ---------------- fp32 -> bf16 bulk convert (vector x4) ----------------
__global__ void cvt_kernel(const float* __restrict__ in, u16* __restrict__ out, int n4) {
  int i = blockIdx.x * blockDim.x + threadIdx.x;
  int stride = gridDim.x * blockDim.x;
  for (; i < n4; i += stride) {
    float4 v = ((const float4*)in)[i];
    ushort4 o;
    o.x = f2bf(v.x); o.y = f2bf(v.y); o.z = f2bf(v.z); o.w = f2bf(v.w);
    ((ushort4*)out)[i] = o;
  }
}

// ---------------- gather span endpoints -> bf16 [L, 2H] ----------------
__global__ void gather_kernel(const float* __restrict__ hidden,
                              const int* __restrict__ bid,
                              const int* __restrict__ sb,
                              const int* __restrict__ se,
                              u16* __restrict__ out) {
  int l = blockIdx.x;
  int t = threadIdx.x;  // 256 threads, 4 floats each per half
  int b  = bid[l];
  const float* p0 = hidden + ((size_t)sb[l] * BB + b) * HH;
  const float* p1 = hidden + ((size_t)se[l] * BB + b) * HH;
  u16* dst = out + (size_t)l * K1;
  float4 v0 = ((const float4*)p0)[t];
  float4 v1 = ((const float4*)p1)[t];
  ushort4 o0; o0.x = f2bf(v0.x); o0.y = f2bf(v0.y); o0.z = f2bf(v0.z); o0.w = f2bf(v0.w);
  ushort4 o1; o1.x = f2bf(v1.x); o1.y = f2bf(v1.y); o1.z = f2bf(v1.z); o1.w = f2bf(v1.w);
  ((ushort4*)dst)[t]          = o0;
  ((ushort4*)(dst + HH))[t]   = o1;
}

// ---------------- 128x128 MFMA GEMM (GEMM1: feat = tanh(...)) ----------
// Proven structure (round-0). LDS XOR-swizzled: LDS[r][c] = G[r][c ^ (r&7)].
__launch_bounds__(256, 2)
__global__ void gemm128_kernel(const u16* __restrict__ A, const u16* __restrict__ B,
                               int Ntot, const float* __restrict__ bias,
                               u16* __restrict__ feat_out) {
  __shared__ __align__(16) u16 As[128 * 64];
  __shared__ __align__(16) u16 Bs[128 * 64];

  const int tid  = threadIdx.x;
  const int lane = tid & 63;
  const int w    = tid >> 6;
  const int wm   = w & 1;
  const int wn   = w >> 1;
  const int q    = lane >> 4;
  const int lm   = lane & 15;
  const int mBase = blockIdx.x * 128;
  const int nBase = blockIdx.y * 128;

  f32x4v acc[4][4];
#pragma unroll
  for (int i = 0; i < 4; ++i)
#pragma unroll
    for (int j = 0; j < 4; ++j) acc[i][j] = (f32x4v){0.f, 0.f, 0.f, 0.f};

  const int srow = w * 32 + (lane >> 3);
  const int scol = ((lane & 7) ^ (lane >> 3)) * 8;
  const u16* Ag = A + (size_t)(mBase + srow) * K1 + scol;
  const u16* Bg = B + (size_t)(nBase + srow) * K1 + scol;

  for (int k0 = 0; k0 < K1; k0 += 64) {
#pragma unroll
    for (int c = 0; c < 4; ++c) {
      __builtin_amdgcn_global_load_lds(
          (const __attribute__((address_space(1))) void*)(Ag + k0 + (size_t)c * 8 * K1),
          (__attribute__((address_space(3))) void*)(As + (w * 32 + c * 8) * 64), 16, 0, 0);
    }
#pragma unroll
    for (int c = 0; c < 4; ++c) {
      __builtin_amdgcn_global_load_lds(
          (const __attribute__((address_space(1))) void*)(Bg + k0 + (size_t)c * 8 * K1),
          (__attribute__((address_space(3))) void*)(Bs + (w * 32 + c * 8) * 64), 16, 0, 0);
    }
    __syncthreads();
#pragma unroll
    for (int kk = 0; kk < 64; kk += 32) {
      bf16x8v af[4], bfr[4];
      const int sw = lm & 7;
#pragma unroll
      for (int i = 0; i < 4; ++i) {
        int row = wm * 64 + i * 16 + lm;
        int kch = (kk >> 3) + q;
        af[i] = *(const bf16x8v*)(As + row * 64 + ((kch ^ sw) << 3));
      }
#pragma unroll
      for (int j = 0; j < 4; ++j) {
        int row = wn * 64 + j * 16 + lm;
        int kch = (kk >> 3) + q;
        bfr[j] = *(const bf16x8v*)(Bs + row * 64 + ((kch ^ sw) << 3));
      }
#pragma unroll
      for (int i = 0; i < 4; ++i)
#pragma unroll
        for (int j = 0; j < 4; ++j)
          acc[i][j] = __builtin_amdgcn_mfma_f32_16x16x32_bf16(af[i], bfr[j], acc[i][j], 0, 0, 0);
    }
    __syncthreads();
  }

  float bj[4];
#pragma unroll
  for (int j = 0; j < 4; ++j) bj[j] = bias[nBase + wn * 64 + j * 16 + lm];
#pragma unroll
  for (int i = 0; i < 4; ++i)
#pragma unroll
    for (int j = 0; j < 4; ++j)
#pragma unroll
      for (int r = 0; r < 4; ++r) {
        int tr = wm * 64 + i * 16 + q * 4 + r;
        int tc = wn * 64 + j * 16 + lm;
        float v = tanhf(acc[i][j][r] + bj[j]);
        feat_out[(size_t)(mBase + tr) * Ntot + nBase + tc] = f2bf(v);
      }
}

// ---------------- 256x256 8-wave pipelined MFMA GEMM + fused softmax ----
// Fragment-level software pipeline with counted lgkmcnt (LDS analog of T4):
// read-group k+1 issues during MFMA group k; LDS returns are FIFO so
// lgkmcnt(N) retires exactly the oldest group. Only 2 barriers per K-tile:
//   B1: after per-wave lgkmcnt(0) -> buf p globally drained -> restage safe
//   B2: after counted vmcnt(8)    -> tile t+1's stage loads visible to all
// Next-tile fragment reads are issued before MFMA G3 so G3 covers their
// latency across the tile boundary. vmcnt never drains to 0 mid-loop.
#define STAGE256(pp, k0) do {                                                       \
  _Pragma("unroll")                                                                 \
  for (int c = 0; c < 4; ++c)                                                       \
    __builtin_amdgcn_global_load_lds(                                               \
        (const __attribute__((address_space(1))) void*)(Ag + (k0) + (size_t)c * 8 * DD), \
        (__attribute__((address_space(3))) void*)(&As[pp][(w * 32 + c * 8) * 64]), 16, 0, 0); \
  _Pragma("unroll")                                                                 \
  for (int c = 0; c < 4; ++c)                                                       \
    __builtin_amdgcn_global_load_lds(                                               \
        (const __attribute__((address_space(1))) void*)(Bg + (k0) + (size_t)c * 8 * DD), \
        (__attribute__((address_space(3))) void*)(&Bs[pp][(w * 32 + c * 8) * 64]), 16, 0, 0); \
} while (0)

#define MFMA_G(base, av, bv) do {                                                   \
  _Pragma("unroll")                                                                 \
  for (int i_ = 0; i_ < 4; ++i_)                                                    \
    _Pragma("unroll")                                                               \
    for (int j_ = 0; j_ < 4; ++j_)                                                  \
      acc[(base) + i_][j_] = __builtin_amdgcn_mfma_f32_16x16x32_bf16(               \
          av[i_], bv[j_], acc[(base) + i_][j_], 0, 0, 0);                           \
} while (0)

#define SB __builtin_amdgcn_sched_barrier(0)

__launch_bounds__(512, 2)
__global__ void gemm256_kernel(const u16* __restrict__ A, const u16* __restrict__ B,
                               const int* __restrict__ tags,
                               float* __restrict__ pmax, float* __restrict__ psum,
                               float* __restrict__ ltag) {
  __shared__ __align__(16) u16 As[2][256 * 64];
  __shared__ __align__(16) u16 Bs[2][256 * 64];
  __shared__ float rmax[4][256];
  __shared__ float rsum[4][256];

  const int tid  = threadIdx.x;
  const int lane = tid & 63;
  const int w    = tid >> 6;       // wave 0..7
  const int wm   = w >> 2;         // wave row (M): 0..1 -> 128 rows each
  const int wn   = w & 3;          // wave col (N): 0..3 -> 64 cols each
  const int q    = lane >> 4;
  const int lm   = lane & 15;
  const int sw   = lm & 15 & 7;
  // T1 XCD swizzle: grid (16,125) = 2000 blocks, 2000/8 = 250 (bijective)
  const int lin = blockIdx.y * 16 + blockIdx.x;
  const int nl  = (lin & 7) * 250 + (lin >> 3);
  const int bx  = nl & 15;
  const int by  = nl >> 4;
  const int mBase = bx * 256;
  const int nBase = by * 256;

  f32x4v acc[8][4];
#pragma unroll
  for (int i = 0; i < 8; ++i)
#pragma unroll
    for (int j = 0; j < 4; ++j) acc[i][j] = (f32x4v){0.f, 0.f, 0.f, 0.f};

  const int srow = w * 32 + (lane >> 3);
  const int scol = ((lane & 7) ^ (lane >> 3)) * 8;   // swizzled source column
  const u16* Ag = A + (size_t)(mBase + srow) * DD + scol;
  const u16* Bg = B + (size_t)(nBase + srow) * DD + scol;

  // per-lane LDS read offsets (u16 units)
  const int aoff = (wm * 128 + lm) * 64;
  const int boff = (wn * 64 + lm) * 64;
  const int c0 = (q ^ sw) << 3;          // k-lo chunk (swizzled)
  const int c1 = ((q + 4) ^ sw) << 3;    // k-hi chunk (swizzled)

  // prologue: stage tiles 0 and 1; wait tile 0 (tile 1's 8 stay in flight)
  STAGE256(0, 0);
  STAGE256(1, 64);
  asm volatile("s_waitcnt vmcnt(8)" ::: "memory");
  __builtin_amdgcn_s_barrier();
  SB;
  bf16x8v a0[4], b0[4], a1[4];
#pragma unroll
  for (int i = 0; i < 4; ++i) a0[i] = *(const bf16x8v*)(&As[0][0] + aoff + i * 1024 + c0);
#pragma unroll
  for (int j = 0; j < 4; ++j) b0[j] = *(const bf16x8v*)(&Bs[0][0] + boff + j * 1024 + c0);
  SB;
#pragma unroll
  for (int i = 0; i < 4; ++i) a1[i] = *(const bf16x8v*)(&As[0][0] + aoff + (i + 4) * 1024 + c0);
  SB;

  const int NT = DD / 64;   // 16 K-tiles
#pragma unroll 2
  for (int t = 0; t < NT; ++t) {
    const int p = t & 1;
    const u16* Asp = &As[p][0];
    const u16* Bsp = &Bs[p][0];
    const u16* Asn = &As[p ^ 1][0];
    const u16* Bsn = &Bs[p ^ 1][0];

    // G0: acc[0..3] @ c0  (a1's 4 reads still in flight)
    asm volatile("s_waitcnt lgkmcnt(4)" ::: "memory");
    SB;
    __builtin_amdgcn_s_setprio(1);
    MFMA_G(0, a0, b0);
    __builtin_amdgcn_s_setprio(0);
    bf16x8v a2[4], b1[4];
#pragma unroll
    for (int i = 0; i < 4; ++i) a2[i] = *(const bf16x8v*)(Asp + aoff + i * 1024 + c1);
#pragma unroll
    for (int j = 0; j < 4; ++j) b1[j] = *(const bf16x8v*)(Bsp + boff + j * 1024 + c1);
    SB;

    // G1: acc[4..7] @ c0  (a2/b1's 8 reads in flight)
    asm volatile("s_waitcnt lgkmcnt(8)" ::: "memory");
    SB;
    __builtin_amdgcn_s_setprio(1);
    MFMA_G(4, a1, b0);
    __builtin_amdgcn_s_setprio(0);
    bf16x8v a3[4];
#pragma unroll
    for (int i = 0; i < 4; ++i) a3[i] = *(const bf16x8v*)(Asp + aoff + (i + 4) * 1024 + c1);
    SB;

    // G2: acc[0..3] @ c1  (a3's 4 reads in flight)
    asm volatile("s_waitcnt lgkmcnt(4)" ::: "memory");
    SB;
    __builtin_amdgcn_s_setprio(1);
    MFMA_G(0, a2, b1);
    __builtin_amdgcn_s_setprio(0);

    // drain all reads of buf p (per-wave), then certify globally
    asm volatile("s_waitcnt lgkmcnt(0)" ::: "memory");
    SB;
    __builtin_amdgcn_s_barrier();      // B1: buf p drained by every wave
    SB;
    if (t + 2 < NT) STAGE256(p, (t + 2) * 64);   // restage buf p for t+2
    if (t + 1 < NT) {
      if (t + 2 < NT) {
        asm volatile("s_waitcnt vmcnt(8)" ::: "memory");  // t+1 done, t+2 in flight
      } else {
        asm volatile("s_waitcnt vmcnt(0)" ::: "memory");  // final drain
      }
      SB;
      __builtin_amdgcn_s_barrier();    // B2: tile t+1 visible to all waves
      SB;
      // prefetch next tile's G0/G1 fragments (latency covered by MFMA G3)
#pragma unroll
      for (int i = 0; i < 4; ++i) a0[i] = *(const bf16x8v*)(Asn + aoff + i * 1024 + c0);
#pragma unroll
      for (int j = 0; j < 4; ++j) b0[j] = *(const bf16x8v*)(Bsn + boff + j * 1024 + c0);
      SB;
#pragma unroll
      for (int i = 0; i < 4; ++i) a1[i] = *(const bf16x8v*)(Asn + aoff + (i + 4) * 1024 + c0);
      SB;
    }

    // G3: acc[4..7] @ c1 (register-only; overlaps next-tile ds latency)
    __builtin_amdgcn_s_setprio(1);
    MFMA_G(4, a3, b1);
    __builtin_amdgcn_s_setprio(0);
  }

  // ---- fused softmax partials over this block's 256 cols ----
  // C/D layout: col = lane&15, row = q*4 + r
#pragma unroll
  for (int i = 0; i < 8; ++i)
#pragma unroll
    for (int r = 0; r < 4; ++r) {
      float m = fmaxf(fmaxf(acc[i][0][r], acc[i][1][r]),
                      fmaxf(acc[i][2][r], acc[i][3][r]));
#pragma unroll
      for (int off = 1; off < 16; off <<= 1) m = fmaxf(m, __shfl_xor(m, off, 64));
      if (lm == 0) rmax[wn][wm * 128 + i * 16 + q * 4 + r] = m;
    }
  __syncthreads();
#pragma unroll
  for (int i = 0; i < 8; ++i)
#pragma unroll
    for (int r = 0; r < 4; ++r) {
      int tr = wm * 128 + i * 16 + q * 4 + r;
      float M = fmaxf(fmaxf(rmax[0][tr], rmax[1][tr]),
                      fmaxf(rmax[2][tr], rmax[3][tr]));
      float s = __expf(acc[i][0][r] - M) + __expf(acc[i][1][r] - M) +
                __expf(acc[i][2][r] - M) + __expf(acc[i][3][r] - M);
#pragma unroll
      for (int off = 1; off < 16; off <<= 1) s += __shfl_xor(s, off, 64);
      if (lm == 0) rsum[wn][tr] = s;
    }
  __syncthreads();
  if (tid < 256) {
    float M = fmaxf(fmaxf(rmax[0][tid], rmax[1][tid]),
                    fmaxf(rmax[2][tid], rmax[3][tid]));
    float S = rsum[0][tid] + rsum[1][tid] + rsum[2][tid] + rsum[3][tid];
    pmax[(size_t)by * LSPANS + mBase + tid] = M;
    psum[(size_t)by * LSPANS + mBase + tid] = S;
  }
  // tag logit capture (exactly one matching column per row globally)
#pragma unroll
  for (int i = 0; i < 8; ++i)
#pragma unroll
    for (int r = 0; r < 4; ++r) {
      int tr = wm * 128 + i * 16 + q * 4 + r;
      int tg = tags[mBase + tr];
#pragma unroll
      for (int j = 0; j < 4; ++j) {
        int gc = nBase + wn * 64 + j * 16 + lm;
        if (tg == gc) ltag[mBase + tr] = acc[i][j][r];
      }
    }
}

// ---------------- merge partials, weighted-mean NLL ----------------
__global__ void finalize_kernel(const float* __restrict__ pmax, const float* __restrict__ psum,
                                const float* __restrict__ ltag, const int* __restrict__ tags,
                                const float* __restrict__ dprob, float* __restrict__ out) {
  int l = blockIdx.x * blockDim.x + threadIdx.x;  // 16 x 256 = 4096
  const float* pm = pmax + l;
  const float* ps = psum + l;
  float M = -1e30f;
  for (int t = 0; t < NT2; ++t) M = fmaxf(M, pm[(size_t)t * LSPANS]);
  float S = 0.f;
  for (int t = 0; t < NT2; ++t) S += ps[(size_t)t * LSPANS] * __expf(pm[(size_t)t * LSPANS] - M);
  float nll = M + logf(S) - ltag[l];
  float wgt = 1.0f - dprob[tags[l]];
  float val = nll * wgt * (1.0f / (4096.0f + 1e-5f));
  __shared__ float red[4];
#pragma unroll
  for (int off = 32; off; off >>= 1) val += __shfl_down(val, off, 64);
  if ((threadIdx.x & 63) == 0) red[threadIdx.x >> 6] = val;
  __syncthreads();
  if (threadIdx.x == 0) atomicAdd(out, red[0] + red[1] + red[2] + red[3]);
}

extern "C" void kernel_launch(void* const* d_in, const int* in_sizes, int n_in,
                              void* d_out, int out_size, void* d_ws, size_t ws_size,
                              hipStream_t stream) {
  const float* hidden = (const float*)d_in[0];
  const float* W1     = (const float*)d_in[1];
  const float* b1     = (const float*)d_in[2];
  const float* Wout   = (const float*)d_in[3];
  const float* dprob  = (const float*)d_in[4];
  const int*   bid    = (const int*)d_in[5];
  const int*   sb     = (const int*)d_in[6];
  const int*   se     = (const int*)d_in[7];
  const int*   tags   = (const int*)d_in[8];
  float* out = (float*)d_out;

  char* ws = (char*)d_ws;
  u16* A1    = (u16*)ws;                 ws += (size_t)LSPANS * K1 * 2;      // 16.78 MB
  u16* W1b   = (u16*)ws;                 ws += (size_t)DD * K1 * 2;          //  4.19 MB
  u16* Woutb = (u16*)ws;                 ws += (size_t)VV * DD * 2;          // 65.54 MB
  u16* feat  = (u16*)ws;                 ws += (size_t)LSPANS * DD * 2;      //  8.39 MB
  float* pmax = (float*)ws;              ws += (size_t)NT2 * LSPANS * 4;     //  2.05 MB
  float* psum = (float*)ws;              ws += (size_t)NT2 * LSPANS * 4;     //  2.05 MB
  float* ltag = (float*)ws;              ws += (size_t)LSPANS * 4;

  hipMemsetAsync(d_out, 0, sizeof(float), stream);

  // bf16 conversions
  {
    int n4 = DD * K1 / 4;
    cvt_kernel<<<(n4 + 255) / 256, 256, 0, stream>>>(W1, W1b, n4);
  }
  {
    int n4 = VV * DD / 4;
    cvt_kernel<<<(n4 + 255) / 256, 256, 0, stream>>>(Wout, Woutb, n4);
  }
  // gather span endpoint embeddings
  gather_kernel<<<LSPANS, 256, 0, stream>>>(hidden, bid, sb, se, A1);

  // GEMM1: feat = tanh(A1 @ W1^T + b1)   [4096 x 1024]
  gemm128_kernel<<<dim3(LSPANS / 128, DD / 128), 256, 0, stream>>>(
      A1, W1b, DD, b1, feat);

  // GEMM2: logits tiles + fused softmax partials   [4096 x 32000], 256^2 pipelined
  gemm256_kernel<<<dim3(LSPANS / 256, VV / 256), 512, 0, stream>>>(
      feat, Woutb, tags, pmax, psum, ltag);

  // merge + weighted mean
  finalize_kernel<<<LSPANS / 256, 256, 0, stream>>>(pmax, psum, ltag, tags, dprob, out);
}

// Round 3
// 587.151 us; speedup vs baseline: 1.2261x; 1.2261x over previous
//
#include <hip/hip_runtime.h>
#include <hip/hip_bf16.h>

#define LSPANS 4096
#define BB 32
#define HH 1024
#define DD 1024
#define VV 32000
#define K1 2048   // 2H
#define NT2 250   // V / 128

typedef unsigned short u16;
typedef __attribute__((ext_vector_type(8))) short bf16x8v;
typedef __attribute__((ext_vector_type(4))) float f32x4v;

__device__ __forceinline__ u16 f2bf(float x) {
  union { float f; unsigned u; } v; v.f = x;
  unsigned r = (v.u >> 16) & 1u;
  return (u16)((v.u + 0x7fffu + r) >> 16);
}

// ---------------- fp32 -> bf16 bulk convert (vector x4) ----------------
__global__ void cvt_kernel(const float* __restrict__ in, u16* __restrict__ out, int n4) {
  int i = blockIdx.x * blockDim.x + threadIdx.x;
  int stride = gridDim.x * blockDim.x;
  for (; i < n4; i += stride) {
    float4 v = ((const float4*)in)[i];
    ushort4 o;
    o.x = f2bf(v.x); o.y = f2bf(v.y); o.z = f2bf(v.z); o.w = f2bf(v.w);
    ((ushort4*)out)[i] = o;
  }
}

// ---------------- gather span endpoints -> bf16 [L, 2H] ----------------
__global__ void gather_kernel(const float* __restrict__ hidden,
                              const int* __restrict__ bid,
                              const int* __restrict__ sb,
                              const int* __restrict__ se,
                              u16* __restrict__ out) {
  int l = blockIdx.x;
  int t = threadIdx.x;  // 256 threads, 4 floats each per half
  int b  = bid[l];
  const float* p0 = hidden + ((size_t)sb[l] * BB + b) * HH;
  const float* p1 = hidden + ((size_t)se[l] * BB + b) * HH;
  u16* dst = out + (size_t)l * K1;
  float4 v0 = ((const float4*)p0)[t];
  float4 v1 = ((const float4*)p1)[t];
  ushort4 o0; o0.x = f2bf(v0.x); o0.y = f2bf(v0.y); o0.z = f2bf(v0.z); o0.w = f2bf(v0.w);
  ushort4 o1; o1.x = f2bf(v1.x); o1.y = f2bf(v1.y); o1.z = f2bf(v1.z); o1.w = f2bf(v1.w);
  ((ushort4*)dst)[t]          = o0;
  ((ushort4*)(dst + HH))[t]   = o1;
}

// ---------------- 128x128 MFMA GEMM (round-0 proven; used for GEMM2) ----
// LDS layout is XOR-swizzled: LDS[r][chunk c] holds global chunk (c ^ (r&7)),
// chunks are 8 u16 = 16 B. global_load_lds forces lane i -> LDS offset i*16B,
// so the swizzle is applied on the global SOURCE address. Fragment reads use
// chunk = kch ^ (row&7).
// EPI=1: out = tanh(acc + bias) -> bf16 feat.  EPI=2: fused softmax partials.
template <int K_, int EPI>
__launch_bounds__(256, 2)
__global__ void gemm_kernel(const u16* __restrict__ A, const u16* __restrict__ B,
                            int Ntot,
                            const float* __restrict__ bias, u16* __restrict__ feat_out,
                            const int* __restrict__ tags,
                            float* __restrict__ pmax, float* __restrict__ psum,
                            float* __restrict__ ltag) {
  __shared__ __align__(16) u16 As[128 * 64];
  __shared__ __align__(16) u16 Bs[128 * 64];
  __shared__ float rmax[2][128];
  __shared__ float rsum[2][128];
  __shared__ int   stags[128];

  const int tid  = threadIdx.x;
  const int lane = tid & 63;
  const int w    = tid >> 6;       // wave 0..3
  const int wm   = w & 1;          // wave row (M)
  const int wn   = w >> 1;         // wave col (N)
  const int q    = lane >> 4;      // quad 0..3
  const int lm   = lane & 15;
  const int mBase = blockIdx.x * 128;
  const int nBase = blockIdx.y * 128;

  if (EPI == 2 && tid < 128) stags[tid] = tags[mBase + tid];

  f32x4v acc[4][4];
#pragma unroll
  for (int i = 0; i < 4; ++i)
#pragma unroll
    for (int j = 0; j < 4; ++j) acc[i][j] = (f32x4v){0.f, 0.f, 0.f, 0.f};

  const int srow = w * 32 + (lane >> 3);
  const int scol = ((lane & 7) ^ (lane >> 3)) * 8;   // swizzled source column
  const u16* Ag = A + (size_t)(mBase + srow) * K_ + scol;
  const u16* Bg = B + (size_t)(nBase + srow) * K_ + scol;

  for (int k0 = 0; k0 < K_; k0 += 64) {
#pragma unroll
    for (int c = 0; c < 4; ++c) {
      __builtin_amdgcn_global_load_lds(
          (const __attribute__((address_space(1))) void*)(Ag + k0 + (size_t)c * 8 * K_),
          (__attribute__((address_space(3))) void*)(As + (w * 32 + c * 8) * 64), 16, 0, 0);
    }
#pragma unroll
    for (int c = 0; c < 4; ++c) {
      __builtin_amdgcn_global_load_lds(
          (const __attribute__((address_space(1))) void*)(Bg + k0 + (size_t)c * 8 * K_),
          (__attribute__((address_space(3))) void*)(Bs + (w * 32 + c * 8) * 64), 16, 0, 0);
    }
    __syncthreads();
#pragma unroll
    for (int kk = 0; kk < 64; kk += 32) {
      bf16x8v af[4], bfr[4];
      const int sw = lm & 7;
#pragma unroll
      for (int i = 0; i < 4; ++i) {
        int row = wm * 64 + i * 16 + lm;
        int kch = (kk >> 3) + q;
        af[i] = *(const bf16x8v*)(As + row * 64 + ((kch ^ sw) << 3));
      }
#pragma unroll
      for (int j = 0; j < 4; ++j) {
        int row = wn * 64 + j * 16 + lm;
        int kch = (kk >> 3) + q;
        bfr[j] = *(const bf16x8v*)(Bs + row * 64 + ((kch ^ sw) << 3));
      }
#pragma unroll
      for (int i = 0; i < 4; ++i)
#pragma unroll
        for (int j = 0; j < 4; ++j)
          acc[i][j] = __builtin_amdgcn_mfma_f32_16x16x32_bf16(af[i], bfr[j], acc[i][j], 0, 0, 0);
    }
    __syncthreads();
  }

  // C/D layout: col = lane&15, row = quad*4 + reg
  if constexpr (EPI == 1) {
    float bj[4];
#pragma unroll
    for (int j = 0; j < 4; ++j) bj[j] = bias[nBase + wn * 64 + j * 16 + lm];
#pragma unroll
    for (int i = 0; i < 4; ++i)
#pragma unroll
      for (int j = 0; j < 4; ++j)
#pragma unroll
        for (int r = 0; r < 4; ++r) {
          int tr = wm * 64 + i * 16 + q * 4 + r;
          int tc = wn * 64 + j * 16 + lm;
          float v = tanhf(acc[i][j][r] + bj[j]);
          feat_out[(size_t)(mBase + tr) * Ntot + nBase + tc] = f2bf(v);
        }
  }

  if constexpr (EPI == 2) {
    // phase 1: per-row max over this wave's 64 cols -> LDS
#pragma unroll
    for (int i = 0; i < 4; ++i)
#pragma unroll
      for (int r = 0; r < 4; ++r) {
        float m = fmaxf(fmaxf(acc[i][0][r], acc[i][1][r]),
                        fmaxf(acc[i][2][r], acc[i][3][r]));
#pragma unroll
        for (int off = 1; off < 16; off <<= 1) m = fmaxf(m, __shfl_xor(m, off, 64));
        if (lm == 0) rmax[wn][wm * 64 + i * 16 + q * 4 + r] = m;
      }
    __syncthreads();
    // phase 2: sumexp against the full 128-col row max
#pragma unroll
    for (int i = 0; i < 4; ++i)
#pragma unroll
      for (int r = 0; r < 4; ++r) {
        int tr = wm * 64 + i * 16 + q * 4 + r;
        float M = fmaxf(rmax[0][tr], rmax[1][tr]);
        float s = __expf(acc[i][0][r] - M) + __expf(acc[i][1][r] - M) +
                  __expf(acc[i][2][r] - M) + __expf(acc[i][3][r] - M);
#pragma unroll
        for (int off = 1; off < 16; off <<= 1) s += __shfl_xor(s, off, 64);
        if (lm == 0) rsum[wn][tr] = s;
      }
    __syncthreads();
    if (tid < 128) {
      float M = fmaxf(rmax[0][tid], rmax[1][tid]);
      float S = rsum[0][tid] + rsum[1][tid];
      pmax[(size_t)blockIdx.y * LSPANS + mBase + tid] = M;
      psum[(size_t)blockIdx.y * LSPANS + mBase + tid] = S;
    }
    // tag logit capture (exactly one matching column per row globally)
#pragma unroll
    for (int i = 0; i < 4; ++i)
#pragma unroll
      for (int r = 0; r < 4; ++r) {
        int tr = wm * 64 + i * 16 + q * 4 + r;
        int tg = stags[tr];
#pragma unroll
        for (int j = 0; j < 4; ++j) {
          int gc = nBase + wn * 64 + j * 16 + lm;
          if (tg == gc) ltag[mBase + tr] = acc[i][j][r];
        }
      }
  }
}

// ---------------- 128x64 MFMA GEMM for GEMM1 (2 blocks/CU) ----------------
// Same staging/swizzle/fragment patterns as gemm_kernel, BN=64 so the
// 512-block grid gives 2 blocks/CU (2 waves/SIMD) instead of 1 for the
// N=1024 output. Waves: wm = w&1 (64 rows), wn = w>>1 (32 cols).
__launch_bounds__(256, 2)
__global__ void gemm1n64_kernel(const u16* __restrict__ A, const u16* __restrict__ B,
                                const float* __restrict__ bias,
                                u16* __restrict__ feat_out) {
  __shared__ __align__(16) u16 As[128 * 64];
  __shared__ __align__(16) u16 Bs[64 * 64];

  const int tid  = threadIdx.x;
  const int lane = tid & 63;
  const int w    = tid >> 6;
  const int wm   = w & 1;
  const int wn   = w >> 1;
  const int q    = lane >> 4;
  const int lm   = lane & 15;
  const int mBase = blockIdx.x * 128;
  const int nBase = blockIdx.y * 64;

  f32x4v acc[4][2];
#pragma unroll
  for (int i = 0; i < 4; ++i)
#pragma unroll
    for (int j = 0; j < 2; ++j) acc[i][j] = (f32x4v){0.f, 0.f, 0.f, 0.f};

  const int srowA = w * 32 + (lane >> 3);
  const int srowB = w * 16 + (lane >> 3);
  const int scol  = ((lane & 7) ^ (lane >> 3)) * 8;   // swizzled source column
  const u16* Ag = A + (size_t)(mBase + srowA) * K1 + scol;
  const u16* Bg = B + (size_t)(nBase + srowB) * K1 + scol;

  for (int k0 = 0; k0 < K1; k0 += 64) {
#pragma unroll
    for (int c = 0; c < 4; ++c) {
      __builtin_amdgcn_global_load_lds(
          (const __attribute__((address_space(1))) void*)(Ag + k0 + (size_t)c * 8 * K1),
          (__attribute__((address_space(3))) void*)(As + (w * 32 + c * 8) * 64), 16, 0, 0);
    }
#pragma unroll
    for (int c = 0; c < 2; ++c) {
      __builtin_amdgcn_global_load_lds(
          (const __attribute__((address_space(1))) void*)(Bg + k0 + (size_t)c * 8 * K1),
          (__attribute__((address_space(3))) void*)(Bs + (w * 16 + c * 8) * 64), 16, 0, 0);
    }
    __syncthreads();
#pragma unroll
    for (int kk = 0; kk < 64; kk += 32) {
      bf16x8v af[4], bfr[2];
      const int sw = lm & 7;
#pragma unroll
      for (int i = 0; i < 4; ++i) {
        int row = wm * 64 + i * 16 + lm;
        int kch = (kk >> 3) + q;
        af[i] = *(const bf16x8v*)(As + row * 64 + ((kch ^ sw) << 3));
      }
#pragma unroll
      for (int j = 0; j < 2; ++j) {
        int row = wn * 32 + j * 16 + lm;
        int kch = (kk >> 3) + q;
        bfr[j] = *(const bf16x8v*)(Bs + row * 64 + ((kch ^ sw) << 3));
      }
#pragma unroll
      for (int i = 0; i < 4; ++i)
#pragma unroll
        for (int j = 0; j < 2; ++j)
          acc[i][j] = __builtin_amdgcn_mfma_f32_16x16x32_bf16(af[i], bfr[j], acc[i][j], 0, 0, 0);
    }
    __syncthreads();
  }

  float bj[2];
#pragma unroll
  for (int j = 0; j < 2; ++j) bj[j] = bias[nBase + wn * 32 + j * 16 + lm];
#pragma unroll
  for (int i = 0; i < 4; ++i)
#pragma unroll
    for (int j = 0; j < 2; ++j)
#pragma unroll
      for (int r = 0; r < 4; ++r) {
        int tr = wm * 64 + i * 16 + q * 4 + r;
        int tc = wn * 32 + j * 16 + lm;
        float v = tanhf(acc[i][j][r] + bj[j]);
        feat_out[(size_t)(mBase + tr) * DD + nBase + tc] = f2bf(v);
      }
}

// ---------------- merge partials, weighted-mean NLL (wave-per-row) ----------
// pmax/psum layout: [tile t][row l] (t < NT2=250, stride LSPANS).
// One wave per row: lane L caches tiles t = L, L+64, L+128, L+192 in regs,
// butterfly max, then butterfly sum of psum*exp(pmax-M). 1024 blocks x 4 waves
// replaces the old 16-block latency-bound loop.
__global__ void finalize_kernel(const float* __restrict__ pmax, const float* __restrict__ psum,
                                const float* __restrict__ ltag, const int* __restrict__ tags,
                                const float* __restrict__ dprob, float* __restrict__ out) {
  const int lane = threadIdx.x & 63;
  const int wv   = threadIdx.x >> 6;
  const int row  = blockIdx.x * 4 + wv;

  float pmv[4], psv[4];
#pragma unroll
  for (int it = 0; it < 4; ++it) {
    int t = lane + it * 64;
    bool ok = t < NT2;
    pmv[it] = ok ? pmax[(size_t)t * LSPANS + row] : -1e30f;
    psv[it] = ok ? psum[(size_t)t * LSPANS + row] : 0.f;
  }
  float M = fmaxf(fmaxf(pmv[0], pmv[1]), fmaxf(pmv[2], pmv[3]));
#pragma unroll
  for (int off = 1; off < 64; off <<= 1) M = fmaxf(M, __shfl_xor(M, off, 64));
  float s = 0.f;
#pragma unroll
  for (int it = 0; it < 4; ++it) s += psv[it] * __expf(pmv[it] - M);
#pragma unroll
  for (int off = 1; off < 64; off <<= 1) s += __shfl_xor(s, off, 64);

  __shared__ float red[4];
  if (lane == 0) {
    float nll = M + logf(s) - ltag[row];
    float wgt = 1.0f - dprob[tags[row]];
    red[wv] = nll * wgt * (1.0f / (4096.0f + 1e-5f));
  }
  __syncthreads();
  if (threadIdx.x == 0) atomicAdd(out, red[0] + red[1] + red[2] + red[3]);
}

extern "C" void kernel_launch(void* const* d_in, const int* in_sizes, int n_in,
                              void* d_out, int out_size, void* d_ws, size_t ws_size,
                              hipStream_t stream) {
  const float* hidden = (const float*)d_in[0];
  const float* W1     = (const float*)d_in[1];
  const float* b1     = (const float*)d_in[2];
  const float* Wout   = (const float*)d_in[3];
  const float* dprob  = (const float*)d_in[4];
  const int*   bid    = (const int*)d_in[5];
  const int*   sb     = (const int*)d_in[6];
  const int*   se     = (const int*)d_in[7];
  const int*   tags   = (const int*)d_in[8];
  float* out = (float*)d_out;

  char* ws = (char*)d_ws;
  u16* A1    = (u16*)ws;                 ws += (size_t)LSPANS * K1 * 2;      // 16.78 MB
  u16* W1b   = (u16*)ws;                 ws += (size_t)DD * K1 * 2;          //  4.19 MB
  u16* Woutb = (u16*)ws;                 ws += (size_t)VV * DD * 2;          // 65.54 MB
  u16* feat  = (u16*)ws;                 ws += (size_t)LSPANS * DD * 2;      //  8.39 MB
  float* pmax = (float*)ws;              ws += (size_t)NT2 * LSPANS * 4;     //  4.10 MB
  float* psum = (float*)ws;              ws += (size_t)NT2 * LSPANS * 4;     //  4.10 MB
  float* ltag = (float*)ws;              ws += (size_t)LSPANS * 4;

  hipMemsetAsync(d_out, 0, sizeof(float), stream);

  // bf16 conversions
  {
    int n4 = DD * K1 / 4;
    cvt_kernel<<<(n4 + 255) / 256, 256, 0, stream>>>(W1, W1b, n4);
  }
  {
    int n4 = VV * DD / 4;
    cvt_kernel<<<(n4 + 255) / 256, 256, 0, stream>>>(Wout, Woutb, n4);
  }
  // gather span endpoint embeddings
  gather_kernel<<<LSPANS, 256, 0, stream>>>(hidden, bid, sb, se, A1);

  // GEMM1: feat = tanh(A1 @ W1^T + b1)   [4096 x 1024], 128x64 tiles, 512 blocks
  gemm1n64_kernel<<<dim3(LSPANS / 128, DD / 64), 256, 0, stream>>>(
      A1, W1b, b1, feat);

  // GEMM2: logits tiles + fused softmax partials   [4096 x 32000]
  gemm_kernel<DD, 2><<<dim3(LSPANS / 128, NT2), 256, 0, stream>>>(
      feat, Woutb, VV, nullptr, nullptr, tags, pmax, psum, ltag);

  // merge + weighted mean
  finalize_kernel<<<LSPANS / 4, 256, 0, stream>>>(pmax, psum, ltag, tags, dprob, out);
}